// Round 2
// baseline (34.689 us; speedup 1.0000x reference)
//
#include <hip/hip_runtime.h>

// out[b][l] = x[b][perm[b][l]]  — per-row pseudo-random interleave.
// B=1024 rows, L=16384 elements/row (fp32). Row = 64 KiB -> stage in LDS,
// gather from LDS, all global traffic fully coalesced via float4/int4.
//
// Occupancy fix vs r0: LDS/block is pinned at 64 KiB (one full row), so
// blocks/CU is pinned at 2. Use 1024-thread blocks: 2 x 16 waves = 32
// waves/CU (max) instead of 2 x 4 = 8. Perm loads hoisted before the
// staging barrier to overlap with x-staging latency.

constexpr int L = 16384;
constexpr int BLOCK = 1024;
constexpr int VEC = L / 4 / BLOCK;  // 4 float4 / int4 per thread

__global__ __launch_bounds__(BLOCK) void interleave_kernel(
    const float* __restrict__ x,
    const int* __restrict__ perm,
    float* __restrict__ out) {
  extern __shared__ float row[];  // 16384 floats = 64 KiB

  const long long base = (long long)blockIdx.x * L;
  const float4* __restrict__ x4 = reinterpret_cast<const float4*>(x + base);
  const int4* __restrict__ p4 = reinterpret_cast<const int4*>(perm + base);
  float4* __restrict__ row4 = reinterpret_cast<float4*>(row);
  float4* __restrict__ o4 = reinterpret_cast<float4*>(out + base);

  // Issue perm loads first so they are in flight across the staging phase.
  int4 p[VEC];
#pragma unroll
  for (int i = 0; i < VEC; ++i) {
    p[i] = p4[threadIdx.x + i * BLOCK];
  }

  // Stage the row into LDS, coalesced 16 B/lane.
#pragma unroll
  for (int i = 0; i < VEC; ++i) {
    const int idx = threadIdx.x + i * BLOCK;
    row4[idx] = x4[idx];
  }
  __syncthreads();

#pragma unroll
  for (int i = 0; i < VEC; ++i) {
    float4 v;
    v.x = row[p[i].x];
    v.y = row[p[i].y];
    v.z = row[p[i].z];
    v.w = row[p[i].w];
    o4[threadIdx.x + i * BLOCK] = v;
  }
}

extern "C" void kernel_launch(void* const* d_in, const int* in_sizes, int n_in,
                              void* d_out, int out_size, void* d_ws, size_t ws_size,
                              hipStream_t stream) {
  const float* x = (const float*)d_in[0];
  const int* perm = (const int*)d_in[1];
  float* out = (float*)d_out;

  const int B = out_size / L;  // 1024
  interleave_kernel<<<B, BLOCK, L * sizeof(float), stream>>>(x, perm, out);
}